// Round 16
// baseline (455.890 us; speedup 1.0000x reference)
//
#include <hip/hip_runtime.h>
#include <stdint.h>

typedef unsigned long long u64;

__device__ __forceinline__ float sig_(float x) { return 1.0f / (1.0f + expf(-x)); }

#define NCAND 2535
#define NKEEP 300

// ---------------------------------------------------------------------------
// conv1: pair-spatial x z-paired (2 cols x 2 images), OCT=8, CIN=3, SPLIT=1,
// fused bias+lrelu (round-15 form).
// ---------------------------------------------------------------------------
__global__ __launch_bounds__(256) void k_conv1zp(
    const float* __restrict__ in, const float* __restrict__ wgt,
    const float* __restrict__ bias, float* __restrict__ out) {
  constexpr int OCT = 8, CIN = 3, HIN = 416, WIN = 416;
  constexpr int HWIN = 173056, HWOUT = 43264, WOUT = 208, COUT = 32, WP = 104;
  const int fb = blockIdx.x;  // 1360 = 4bp | 85x | 4g
  const int bp = fb & 3;
  const int r = fb >> 2;
  const int x = r % 85, g = r / 85;
  const int b0 = bp * 2;
  const int sp = x * 256 + threadIdx.x;
  if (sp >= 21632) return;  // 208 rows x 104 col-pairs
  const int oy = sp / WP, oxp = sp % WP;
  const int ox0 = oxp * 2;
  const int iy0 = oy * 2, ix0 = oxp * 4;
  const bool okY = (iy0 + 2 < HIN);
  const bool c4v = (ix0 + 4 < WIN);
  const float* inb0 = in + (size_t)b0 * CIN * HWIN + (size_t)iy0 * WIN + ix0;
  const float* inb1 = inb0 + (size_t)CIN * HWIN;
  const float* wb = wgt + (size_t)g * OCT * CIN * 9;

  float a00[OCT], a01[OCT], a10[OCT], a11[OCT];
#pragma unroll
  for (int u = 0; u < OCT; u++) {
    a00[u] = 0.0f;
    a01[u] = 0.0f;
    a10[u] = 0.0f;
    a11[u] = 0.0f;
  }

  auto load15 = [&](float v[15], const float* ip) {
#pragma unroll
    for (int ky = 0; ky < 3; ky++) {
      const bool rok = (ky < 2) || okY;
      const float* rp = ip + ky * WIN;
      float4 p = make_float4(0.f, 0.f, 0.f, 0.f);
      float c4 = 0.f;
      if (rok) {
        p = *(const float4*)rp;  // 16B-aligned: ix0%4==0, WIN%4==0
        if (c4v) c4 = rp[4];
      }
      v[ky * 5 + 0] = p.x;
      v[ky * 5 + 1] = p.y;
      v[ky * 5 + 2] = p.z;
      v[ky * 5 + 3] = p.w;
      v[ky * 5 + 4] = c4;
    }
  };
  auto fmablk4 = [&](const float v0[15], const float v1[15], int ci) {
#pragma unroll
    for (int u = 0; u < OCT; u++) {
#pragma unroll
      for (int ky = 0; ky < 3; ky++) {
#pragma unroll
        for (int kx = 0; kx < 3; kx++) {
          const float w = wb[(size_t)u * (CIN * 9) + ci * 9 + ky * 3 + kx];
          a00[u] = fmaf(v0[ky * 5 + kx], w, a00[u]);
          a01[u] = fmaf(v0[ky * 5 + kx + 2], w, a01[u]);
          a10[u] = fmaf(v1[ky * 5 + kx], w, a10[u]);
          a11[u] = fmaf(v1[ky * 5 + kx + 2], w, a11[u]);
        }
      }
    }
  };

  float vA0[15], vA1[15], vB0[15], vB1[15];
  load15(vA0, inb0);                  // ch0, img b0
  load15(vA1, inb1);                  // ch0, img b1
  load15(vB0, inb0 + HWIN);           // ch1
  load15(vB1, inb1 + HWIN);
  fmablk4(vA0, vA1, 0);
  load15(vA0, inb0 + 2 * HWIN);       // ch2 reuses ch0 buffers
  load15(vA1, inb1 + 2 * HWIN);
  fmablk4(vB0, vB1, 1);
  fmablk4(vA0, vA1, 2);

  float* ob0 =
      out + ((size_t)b0 * COUT + g * OCT) * HWOUT + (size_t)oy * WOUT + ox0;
  float* ob1 = ob0 + (size_t)COUT * HWOUT;
#pragma unroll
  for (int u = 0; u < OCT; u++) {
    const float bi = bias[g * OCT + u];
    float r00 = a00[u] + bi, r01 = a01[u] + bi;
    float r10 = a10[u] + bi, r11 = a11[u] + bi;
    r00 = r00 > 0.0f ? r00 : 0.1f * r00;
    r01 = r01 > 0.0f ? r01 : 0.1f * r01;
    r10 = r10 > 0.0f ? r10 : 0.1f * r10;
    r11 = r11 > 0.0f ? r11 : 0.1f * r11;
    *(float2*)(ob0 + (size_t)u * HWOUT) = make_float2(r00, r01);
    *(float2*)(ob1 + (size_t)u * HWOUT) = make_float2(r10, r11);
  }
}

// ---------------------------------------------------------------------------
// conv2: pair-spatial x z-paired (2 cols x 2 images), OCT=8, SPLIT=1,
// fused bias+lrelu (round-14 proven form).
// ---------------------------------------------------------------------------
__global__ __launch_bounds__(256) void k_conv2zp(
    const float* __restrict__ in, const float* __restrict__ wgt,
    const float* __restrict__ bias, float* __restrict__ out) {
  constexpr int OCT = 8, CIN = 32, HIN = 208, WIN = 208;
  constexpr int HWIN = 43264, HWOUT = 10816, WOUT = 104, COUT = 64, WP = 52;
  const int fb = blockIdx.x;  // 704 = 4bp | 22x | 8g
  const int bp = fb & 3;
  const int r = fb >> 2;
  const int x = r % 22, g = r / 22;
  const int b0 = bp * 2;
  const int sp = x * 256 + threadIdx.x;
  if (sp >= 5408) return;  // 104 rows x 52 col-pairs
  const int oy = sp / WP, oxp = sp % WP;
  const int ox0 = oxp * 2;
  const int iy0 = oy * 2, ix0 = oxp * 4;
  const bool okY = (iy0 + 2 < HIN);
  const bool c4v = (ix0 + 4 < WIN);
  const float* inb0 = in + (size_t)b0 * CIN * HWIN + (size_t)iy0 * WIN + ix0;
  const float* inb1 = inb0 + (size_t)CIN * HWIN;
  const float* wb = wgt + (size_t)g * OCT * CIN * 9;

  float a00[OCT], a01[OCT], a10[OCT], a11[OCT];
#pragma unroll
  for (int u = 0; u < OCT; u++) {
    a00[u] = 0.0f;
    a01[u] = 0.0f;
    a10[u] = 0.0f;
    a11[u] = 0.0f;
  }

  auto load15 = [&](float v[15], const float* ip) {
#pragma unroll
    for (int ky = 0; ky < 3; ky++) {
      const bool rok = (ky < 2) || okY;
      const float* rp = ip + ky * WIN;
      float4 p = make_float4(0.f, 0.f, 0.f, 0.f);
      float c4 = 0.f;
      if (rok) {
        p = *(const float4*)rp;  // 16B-aligned: ix0%4==0, WIN%4==0
        if (c4v) c4 = rp[4];
      }
      v[ky * 5 + 0] = p.x;
      v[ky * 5 + 1] = p.y;
      v[ky * 5 + 2] = p.z;
      v[ky * 5 + 3] = p.w;
      v[ky * 5 + 4] = c4;
    }
  };
  auto fmablk4 = [&](const float v0[15], const float v1[15], int ci) {
#pragma unroll
    for (int u = 0; u < OCT; u++) {
#pragma unroll
      for (int ky = 0; ky < 3; ky++) {
#pragma unroll
        for (int kx = 0; kx < 3; kx++) {
          const float w = wb[(size_t)u * (CIN * 9) + ci * 9 + ky * 3 + kx];
          a00[u] = fmaf(v0[ky * 5 + kx], w, a00[u]);
          a01[u] = fmaf(v0[ky * 5 + kx + 2], w, a01[u]);
          a10[u] = fmaf(v1[ky * 5 + kx], w, a10[u]);
          a11[u] = fmaf(v1[ky * 5 + kx + 2], w, a11[u]);
        }
      }
    }
  };

  float vA0[15], vA1[15], vB0[15], vB1[15];
  load15(vA0, inb0);
  load15(vA1, inb1);
#pragma unroll 1
  for (int ci = 0; ci < CIN; ci += 2) {
    const int cn = (ci + 2) & (CIN - 1);  // clamp final overshoot (wraps)
    load15(vB0, inb0 + (size_t)(ci + 1) * HWIN);
    load15(vB1, inb1 + (size_t)(ci + 1) * HWIN);
    fmablk4(vA0, vA1, ci);
    load15(vA0, inb0 + (size_t)cn * HWIN);
    load15(vA1, inb1 + (size_t)cn * HWIN);
    fmablk4(vB0, vB1, ci + 1);
  }

  float* ob0 =
      out + ((size_t)b0 * COUT + g * OCT) * HWOUT + (size_t)oy * WOUT + ox0;
  float* ob1 = ob0 + (size_t)COUT * HWOUT;
#pragma unroll
  for (int u = 0; u < OCT; u++) {
    const float bi = bias[g * OCT + u];
    float r00 = a00[u] + bi, r01 = a01[u] + bi;
    float r10 = a10[u] + bi, r11 = a11[u] + bi;
    r00 = r00 > 0.0f ? r00 : 0.1f * r00;
    r01 = r01 > 0.0f ? r01 : 0.1f * r01;
    r10 = r10 > 0.0f ? r10 : 0.1f * r10;
    r11 = r11 > 0.0f ? r11 : 0.1f * r11;
    *(float2*)(ob0 + (size_t)u * HWOUT) = make_float2(r00, r01);
    *(float2*)(ob1 + (size_t)u * HWOUT) = make_float2(r10, r11);
  }
}

// ---------------------------------------------------------------------------
// conv3: pair-spatial x z-paired (2 cols x 2 images), OCT=8, SPLIT=2.
// + w4 repack tail for conv4z2 OCT=16:
//   w4r[(g*4+s)*4608 + (cl*16+u)*9 + k], g in [0,16), u in [0,16).
// ---------------------------------------------------------------------------
__global__ __launch_bounds__(256) void k_conv3_repack(
    const float* __restrict__ in, const float* __restrict__ wgt,
    float* __restrict__ P3, const float* __restrict__ w4,
    float* __restrict__ w4r) {
  const int fb = blockIdx.x;
  if (fb < 768) {  // 8(s,bp) * 6x * 16g
    constexpr int OCT = 8, CS = 32, HIN = 104, WIN = 104;
    constexpr int HWIN = 10816, HWOUT = 2704, WOUT = 52, COUT = 128, WP = 26;
    const int low3 = fb & 7;  // s*4 + bp (XCD affinity)
    const int s = low3 >> 2, bp = low3 & 3;
    const int r = fb >> 3;
    const int x = r % 6, g = r / 6;
    const int b0 = bp * 2;
    const int sp = x * 256 + threadIdx.x;
    if (sp >= 1352) return;  // 52 rows x 26 col-pairs
    const int oy = sp / WP, oxp = sp % WP;
    const int ox0 = oxp * 2;
    const int iy0 = oy * 2, ix0 = oxp * 4;
    const bool okY = (iy0 + 2 < HIN);
    const bool c4v = (ix0 + 4 < WIN);
    const float* inb0 =
        in + ((size_t)b0 * 64 + s * CS) * HWIN + (size_t)iy0 * WIN + ix0;
    const float* inb1 = inb0 + (size_t)64 * HWIN;
    const float* wb = wgt + ((size_t)(g * OCT) * 64 + s * CS) * 9;

    float a00[OCT], a01[OCT], a10[OCT], a11[OCT];
#pragma unroll
    for (int u = 0; u < OCT; u++) {
      a00[u] = 0.0f;
      a01[u] = 0.0f;
      a10[u] = 0.0f;
      a11[u] = 0.0f;
    }

    auto load15 = [&](float v[15], const float* ip) {
#pragma unroll
      for (int ky = 0; ky < 3; ky++) {
        const bool rok = (ky < 2) || okY;
        const float* rp = ip + ky * WIN;
        float4 p = make_float4(0.f, 0.f, 0.f, 0.f);
        float c4 = 0.f;
        if (rok) {
          p = *(const float4*)rp;  // 16B-aligned: ix0%4==0, WIN%4==0
          if (c4v) c4 = rp[4];
        }
        v[ky * 5 + 0] = p.x;
        v[ky * 5 + 1] = p.y;
        v[ky * 5 + 2] = p.z;
        v[ky * 5 + 3] = p.w;
        v[ky * 5 + 4] = c4;
      }
    };
    auto fmablk4 = [&](const float v0[15], const float v1[15], int ci) {
#pragma unroll
      for (int u = 0; u < OCT; u++) {
#pragma unroll
        for (int ky = 0; ky < 3; ky++) {
#pragma unroll
          for (int kx = 0; kx < 3; kx++) {
            const float w = wb[(size_t)u * (64 * 9) + ci * 9 + ky * 3 + kx];
            a00[u] = fmaf(v0[ky * 5 + kx], w, a00[u]);
            a01[u] = fmaf(v0[ky * 5 + kx + 2], w, a01[u]);
            a10[u] = fmaf(v1[ky * 5 + kx], w, a10[u]);
            a11[u] = fmaf(v1[ky * 5 + kx + 2], w, a11[u]);
          }
        }
      }
    };

    float vA0[15], vA1[15], vB0[15], vB1[15];
    load15(vA0, inb0);
    load15(vA1, inb1);
#pragma unroll 1
    for (int ci = 0; ci < CS; ci += 2) {
      const int cn = (ci + 2) & (CS - 1);  // clamp final overshoot (wraps)
      load15(vB0, inb0 + (size_t)(ci + 1) * HWIN);
      load15(vB1, inb1 + (size_t)(ci + 1) * HWIN);
      fmablk4(vA0, vA1, ci);
      load15(vA0, inb0 + (size_t)cn * HWIN);
      load15(vA1, inb1 + (size_t)cn * HWIN);
      fmablk4(vB0, vB1, ci + 1);
    }

    float* ob0 =
        P3 + ((size_t)(s * 8 + b0) * COUT + g * OCT) * HWOUT +
        (size_t)oy * WOUT + ox0;
    float* ob1 = ob0 + (size_t)COUT * HWOUT;  // image b0+1, same s-slice
#pragma unroll
    for (int u = 0; u < OCT; u++) {
      *(float2*)(ob0 + (size_t)u * HWOUT) = make_float2(a00[u], a01[u]);
      *(float2*)(ob1 + (size_t)u * HWOUT) = make_float2(a10[u], a11[u]);
    }
    return;
  }
  const int base = (fb - 768) * 256 + threadIdx.x;
  for (int gid = base; gid < 294912; gid += 160 * 256) {
    const int oc = gid / (128 * 9), r = gid % (128 * 9);
    const int ci = r / 9, k = r % 9;
    const int g = oc / 16, u = oc % 16, s = ci / 32, cl = ci % 32;
    w4r[(size_t)(g * 4 + s) * 4608 + (cl * 16 + u) * 9 + k] = w4[gid];
  }
}

// ---------------------------------------------------------------------------
// Fused conv3 reduce + bias + lrelu + ZERO-PAD to 54 rows x 56 cols stride.
// x3p[(b*128+oc)*3024 + y*56 + x], rows/cols >= 52 are 0.
// ---------------------------------------------------------------------------
__global__ __launch_bounds__(256) void k_reduce_pad3(
    const float* __restrict__ P3, const float* __restrict__ bias,
    float* __restrict__ x3p) {
  const int gid = blockIdx.x * 256 + threadIdx.x;
  if (gid >= 8 * 128 * 3024) return;
  const int c = gid / 3024;  // b*128 + oc
  const int r = gid % 3024;
  const int y = r / 56, x = r % 56;
  float a = 0.0f;
  if (y < 52 && x < 52) {
    const int src = c * 2704 + y * 52 + x;
    a = P3[src] + P3[2768896 + src];
    a += bias[c & 127];
    a = a > 0.0f ? a : 0.1f * a;
  }
  x3p[gid] = a;
}

// ---------------------------------------------------------------------------
// conv4: z-paired OCT=16 single-spatial (round-12 form).
// ---------------------------------------------------------------------------
__device__ __forceinline__ void conv4z2_body(const float* __restrict__ in,
                                             const float* __restrict__ wgt,
                                             float* __restrict__ out, int g,
                                             int s, int bp, int x) {
  constexpr int OCT = 16, CS = 32;
  constexpr int PHW = 3024, PW = 56;  // padded 54x56-stride plane
  constexpr int HWOUT = 676, WOUT = 26, COUT = 256;
  const int b0 = bp * 2;
  const int sp = x * 256 + threadIdx.x;
  if (sp >= HWOUT) return;
  const int oy = sp / WOUT, ox = sp % WOUT;
  const float* inb0 =
      in + ((size_t)b0 * 128 + s * CS) * PHW + (size_t)(oy * 2) * PW + ox * 2;
  const float* inb1 = inb0 + (size_t)128 * PHW;  // b1 = b0+1
  const float* wb = wgt + (size_t)(g * 4 + s) * 4608;

  float acc0[OCT], acc1[OCT];
#pragma unroll
  for (int u = 0; u < OCT; u++) {
    acc0[u] = 0.0f;
    acc1[u] = 0.0f;
  }

  auto load9 = [&](float v[9], const float* ip) {
#pragma unroll
    for (int ky = 0; ky < 3; ky++) {
      const float2 p = *(const float2*)(ip + ky * PW);
      v[ky * 3 + 0] = p.x;
      v[ky * 3 + 1] = p.y;
      v[ky * 3 + 2] = ip[ky * PW + 2];
    }
  };
  auto fmablk2 = [&](const float v0[9], const float v1[9], int ci) {
#pragma unroll
    for (int u = 0; u < OCT; u++) {
#pragma unroll
      for (int k = 0; k < 9; k++) {
        const float w = wb[(size_t)(ci * OCT + u) * 9 + k];
        acc0[u] = fmaf(v0[k], w, acc0[u]);
        acc1[u] = fmaf(v1[k], w, acc1[u]);
      }
    }
  };

  float vA0[9], vA1[9], vB0[9], vB1[9];
  load9(vA0, inb0);
  load9(vA1, inb1);
#pragma unroll 1
  for (int ci = 0; ci < CS; ci += 2) {
    // prefetch next channel for both planes. Final overshoot reads stay
    // inside the workspace (values unused; w4r sits above the overshoot).
    load9(vB0, inb0 + (size_t)(ci + 1) * PHW);
    load9(vB1, inb1 + (size_t)(ci + 1) * PHW);
    fmablk2(vA0, vA1, ci);
    load9(vA0, inb0 + (size_t)(ci + 2) * PHW);
    load9(vA1, inb1 + (size_t)(ci + 2) * PHW);
    fmablk2(vB0, vB1, ci + 1);
  }

  float* ob0 = out + ((size_t)(s * 8 + b0) * COUT + g * OCT) * HWOUT + sp;
  float* ob1 = ob0 + (size_t)COUT * HWOUT;  // b1 slice
#pragma unroll
  for (int u = 0; u < OCT; u++) {
    ob0[(size_t)u * HWOUT] = acc0[u];
    ob1[(size_t)u * HWOUT] = acc1[u];
  }
}

// ---------------------------------------------------------------------------
// conv4z2 OCT=16 (768 blocks: 16(bp,s) x 3x x 16g, XCD-swizzled low bits) +
// grid-stride repack (1024 blocks) of w5 (OCT=8 round-0 layout) / wh2 / wh1.
// ---------------------------------------------------------------------------
__global__ __launch_bounds__(256) void k_conv4_repack(
    const float* __restrict__ x3p, const float* __restrict__ w4r,
    float* __restrict__ P, const float* __restrict__ w5,
    const float* __restrict__ wh2, const float* __restrict__ wh1,
    float* __restrict__ w5r, float* __restrict__ wh2r,
    float* __restrict__ wh1r) {
  const int fb = blockIdx.x;
  if (fb < 768) {
    const int low4 = fb & 15;  // bp*4 + s
    const int bp = low4 >> 2, s = low4 & 3;
    const int r = fb >> 4;  // [0,48)
    const int x = r % 3, g = r / 3;
    conv4z2_body(x3p, w4r, P, g, s, bp, x);
    return;
  }
  const int base = (fb - 768) * 256 + threadIdx.x;
  for (int gid = base; gid < 1375488; gid += 1024 * 256) {
    if (gid < 1179648) {  // w5: COUT=512, CIN=256, CS=32, OCT=8 (round-0
      const int oc = gid / (256 * 9), r = gid % (256 * 9);  // proven layout)
      const int ci = r / 9, k = r % 9;
      const int g = oc / 8, u = oc % 8, s = ci / 32, cl = ci % 32;
      w5r[(((size_t)(g * 8 + s) * 32 + cl) * 8 + u) * 9 + k] = w5[gid];
    } else if (gid < 1179648 + 65280) {  // wh2: 255x256, SPLIT=2 -> CS=128
      const int t = gid - 1179648;
      const int oc = t / 256, ci = t % 256;
      const int g = oc / 17, u = oc % 17, s = ci / 128, cl = ci % 128;
      wh2r[((size_t)(g * 2 + s) * 128 + cl) * 17 + u] = wh2[t];
    } else {  // wh1: 255x512, SPLIT=16 -> CS=32
      const int t = gid - 1179648 - 65280;
      const int oc = t / 512, ci = t % 512;
      const int g = oc / 17, u = oc % 17, s = ci / 32, cl = ci % 32;
      wh1r[((size_t)(g * 16 + s) * 32 + cl) * 17 + u] = wh1[t];
    }
  }
}

// ---------------------------------------------------------------------------
// Fused conv4 reduce + bias + lrelu + ZERO-PAD to 27 rows x 28 cols stride.
// x4p[(b*256+oc)*756 + y*28 + x], rows/cols >= 26 are 0.
// ---------------------------------------------------------------------------
__global__ __launch_bounds__(256) void k_reduce_pad4(
    const float* __restrict__ P, const float* __restrict__ bias,
    float* __restrict__ x4p) {
  const int gid = blockIdx.x * 256 + threadIdx.x;
  if (gid >= 8 * 256 * 756) return;
  const int c = gid / 756;  // b*256 + oc
  const int r = gid % 756;
  const int y = r / 28, x = r % 28;
  float a = 0.0f;
  if (y < 26 && x < 26) {
    const int src = c * 676 + y * 26 + x;
#pragma unroll
    for (int s = 0; s < 4; s++) a += P[(size_t)s * 1384448 + src];
    a += bias[c & 255];
    a = a > 0.0f ? a : 0.1f * a;
  }
  x4p[gid] = a;
}

// ---------------------------------------------------------------------------
// 1x1 head body; PAD=true reads the 27x28-stride padded x4p plane.
// ---------------------------------------------------------------------------
template <int CIN, int OCT, int SPLIT, bool PAD>
__device__ __forceinline__ void head_body(const float* __restrict__ in,
                                          const float* __restrict__ wgt,
                                          float* __restrict__ out, int HW,
                                          int bx, int g, int bz) {
  constexpr int CS = CIN / SPLIT;  // multiple of 8
  const int sp = bx * 256 + threadIdx.x;
  if (sp >= HW) return;
  const int oc0 = g * OCT;
  const int b = bz / SPLIT, s = bz % SPLIT;
  const int IHW = PAD ? 756 : HW;
  const int psp = PAD ? (sp / 26) * 28 + (sp % 26) : sp;
  const float* ip = in + ((size_t)b * CIN + s * CS) * IHW + psp;
  const float* wb = wgt + (size_t)(g * SPLIT + s) * CS * OCT;
  float acc[OCT];
#pragma unroll
  for (int u = 0; u < OCT; u++) acc[u] = 0.0f;

  auto fma4 = [&](const float v[4], int base) {
#pragma unroll
    for (int j = 0; j < 4; j++) {
#pragma unroll
      for (int u = 0; u < OCT; u++)
        acc[u] = fmaf(v[j], wb[(size_t)(base + j) * OCT + u], acc[u]);
    }
  };

  float vA[4], vB[4];
#pragma unroll
  for (int j = 0; j < 4; j++) {
    vA[j] = ip[(size_t)j * IHW];
    vB[j] = ip[(size_t)(4 + j) * IHW];
  }
  for (int c0 = 0; c0 < CS; c0 += 8) {
    float nA[4];
    if (c0 + 8 < CS) {
#pragma unroll
      for (int j = 0; j < 4; j++) nA[j] = ip[(size_t)(c0 + 8 + j) * IHW];
    }
    fma4(vA, c0);
    float nB[4];
    if (c0 + 12 < CS) {
#pragma unroll
      for (int j = 0; j < 4; j++) nB[j] = ip[(size_t)(c0 + 12 + j) * IHW];
    }
    fma4(vB, c0 + 4);
    if (c0 + 8 < CS) {
#pragma unroll
      for (int j = 0; j < 4; j++) vA[j] = nA[j];
    }
    if (c0 + 12 < CS) {
#pragma unroll
      for (int j = 0; j < 4; j++) vB[j] = nB[j];
    }
  }
#pragma unroll
  for (int u = 0; u < OCT; u++)
    out[((size_t)(s * 8 + b) * 255 + oc0 + u) * HW + sp] = acc[u];
}

// ---------------------------------------------------------------------------
// conv5: z4 OCT=8 — one thread computes the same (g, spatial) output for
// FOUR batch images. Weight batch/channel = 72 floats (fits SGPR file ->
// compiler can double-buffer the uniform weight stream); aux-ops/FMA 0.375.
// w5r layout: round-0 proven OCT=8 [((g*8+s)*32+cl)*8+u]*9+k, g in [0,64).
// ---------------------------------------------------------------------------
__device__ __forceinline__ void conv5z4_body(const float* __restrict__ in,
                                             const float* __restrict__ wgt,
                                             float* __restrict__ out, int g,
                                             int s, int bq) {
  constexpr int OCT = 8, CS = 32;
  constexpr int PHW = 756, PW = 28;  // padded 27x28-stride plane
  constexpr int HWOUT = 169, WOUT = 13, COUT = 512;
  const int b0 = bq * 4;
  const int sp = threadIdx.x;
  if (sp >= HWOUT) return;
  const int oy = sp / WOUT, ox = sp % WOUT;
  const float* inb0 =
      in + ((size_t)b0 * 256 + s * CS) * PHW + (size_t)(oy * 2) * PW + ox * 2;
  const size_t IMG = (size_t)256 * PHW;
  const float* wb = wgt + (size_t)(g * 8 + s) * 2304;

  float a0[OCT], a1[OCT], a2[OCT], a3[OCT];
#pragma unroll
  for (int u = 0; u < OCT; u++) {
    a0[u] = 0.0f;
    a1[u] = 0.0f;
    a2[u] = 0.0f;
    a3[u] = 0.0f;
  }

  auto load9 = [&](float v[9], const float* ip) {
#pragma unroll
    for (int ky = 0; ky < 3; ky++) {
      const float2 p = *(const float2*)(ip + ky * PW);
      v[ky * 3 + 0] = p.x;
      v[ky * 3 + 1] = p.y;
      v[ky * 3 + 2] = ip[ky * PW + 2];
    }
  };
  auto fmablkz4 = [&](const float v0[9], const float v1[9], const float v2[9],
                      const float v3[9], int ci) {
#pragma unroll
    for (int u = 0; u < OCT; u++) {
#pragma unroll
      for (int k = 0; k < 9; k++) {
        const float w = wb[(size_t)(ci * OCT + u) * 9 + k];
        a0[u] = fmaf(v0[k], w, a0[u]);
        a1[u] = fmaf(v1[k], w, a1[u]);
        a2[u] = fmaf(v2[k], w, a2[u]);
        a3[u] = fmaf(v3[k], w, a3[u]);
      }
    }
  };

  float vA0[9], vA1[9], vA2[9], vA3[9];
  float vB0[9], vB1[9], vB2[9], vB3[9];
  load9(vA0, inb0);
  load9(vA1, inb0 + IMG);
  load9(vA2, inb0 + 2 * IMG);
  load9(vA3, inb0 + 3 * IMG);
#pragma unroll 1
  for (int ci = 0; ci < CS; ci += 2) {
    // prefetch next channel for all 4 planes. Final overshoot (b=7,s=7)
    // ends ~2.2K floats past x4p -> dead gap below f2 (values unused).
    load9(vB0, inb0 + (size_t)(ci + 1) * PHW);
    load9(vB1, inb0 + IMG + (size_t)(ci + 1) * PHW);
    load9(vB2, inb0 + 2 * IMG + (size_t)(ci + 1) * PHW);
    load9(vB3, inb0 + 3 * IMG + (size_t)(ci + 1) * PHW);
    fmablkz4(vA0, vA1, vA2, vA3, ci);
    load9(vA0, inb0 + (size_t)(ci + 2) * PHW);
    load9(vA1, inb0 + IMG + (size_t)(ci + 2) * PHW);
    load9(vA2, inb0 + 2 * IMG + (size_t)(ci + 2) * PHW);
    load9(vA3, inb0 + 3 * IMG + (size_t)(ci + 2) * PHW);
    fmablkz4(vB0, vB1, vB2, vB3, ci + 1);
  }

  float* ob0 = out + ((size_t)(s * 8 + b0) * COUT + g * OCT) * HWOUT + sp;
  const size_t OB = (size_t)COUT * HWOUT;  // next image slice
#pragma unroll
  for (int u = 0; u < OCT; u++) {
    ob0[(size_t)u * HWOUT] = a0[u];
    ob0[OB + (size_t)u * HWOUT] = a1[u];
    ob0[2 * OB + (size_t)u * HWOUT] = a2[u];
    ob0[3 * OB + (size_t)u * HWOUT] = a3[u];
  }
}

// ---------------------------------------------------------------------------
// Merged launch, XCD-swizzled: conv5 z4 fb<1024 (fb%8 == s; 2bq x 64g);
// head2 blocks 1024..1743 (id%8 == z'%8).
// ---------------------------------------------------------------------------
__global__ __launch_bounds__(256) void k_h2c5(const float* __restrict__ x4p,
                                              const float* __restrict__ w5r,
                                              const float* __restrict__ wh2r,
                                              float* __restrict__ P5,
                                              float* __restrict__ Ph2) {
  const int fb = blockIdx.x;
  if (fb < 1024) {  // 8s * 2bq * 64g
    const int s = fb & 7;
    const int r = fb >> 3;
    const int bq = r & 1;
    const int g = r >> 1;
    conv5z4_body(x4p, w5r, P5, g, s, bq);
  } else {
    const int id = fb - 1024;  // 720 = 8 * 3x * 2zhi * 15g
    const int low3 = id & 7;
    int r = id >> 3;
    const int x = r % 3;
    r /= 3;
    const int zhi = r & 1;
    const int g = r >> 1;
    head_body<256, 17, 2, true>(x4p, wh2r, Ph2, 676, x, g, low3 + 8 * zhi);
  }
}

__global__ __launch_bounds__(256) void k_head1(const float* __restrict__ i,
                                               const float* __restrict__ w,
                                               float* __restrict__ o) {
  head_body<512, 17, 16, false>(i, w, o, 169, blockIdx.x, blockIdx.y,
                                blockIdx.z);
}

// ---------------------------------------------------------------------------
// Reduce SPLIT partials (slice-major, deterministic) + bias (+ lrelu).
// ---------------------------------------------------------------------------
template <int SPLIT, bool LRELU>
__device__ __forceinline__ void reduce_body(const float* __restrict__ P,
                                            const float* __restrict__ bias,
                                            float* __restrict__ out, int COUT,
                                            int HWOUT, int N, int gid) {
  if (gid >= N) return;
  float a = 0.0f;
#pragma unroll
  for (int s = 0; s < SPLIT; s++) a += P[(size_t)s * N + gid];
  const int oc = (gid / HWOUT) % COUT;
  a += bias[oc];
  if (LRELU) a = a > 0.0f ? a : 0.1f * a;
  out[gid] = a;
}

template <int SPLIT, bool LRELU>
__global__ __launch_bounds__(256) void reduce_bias(
    const float* __restrict__ P, const float* __restrict__ bias,
    float* __restrict__ out, int COUT, int HWOUT, int N) {
  reduce_body<SPLIT, LRELU>(P, bias, out, COUT, HWOUT, N,
                            blockIdx.x * 256 + threadIdx.x);
}

// Merged reduce for conv5 (SPLIT=8, lrelu -> x5) + head2 (SPLIT=2 -> f2).
__global__ __launch_bounds__(256) void k_reduce_h2c5(
    const float* __restrict__ P5, const float* __restrict__ Ph2,
    const float* __restrict__ b5, const float* __restrict__ bh2,
    float* __restrict__ x5, float* __restrict__ f2) {
  const int fb = blockIdx.x;
  if (fb < 2704) {
    reduce_body<8, true>(P5, b5, x5, 512, 169, 692224,
                         fb * 256 + threadIdx.x);
  } else {
    reduce_body<2, false>(Ph2, bh2, f2, 255, 676, 1379040,
                          (fb - 2704) * 256 + threadIdx.x);
  }
}

// ---------------------------------------------------------------------------
// Decode both heads -> cand[b][i][8] = {y1,x1,y2,x2,obj,cc,label,score} and
// packed keys (score_bits<<32)|(0xFFFFFFFF-i) matching jax.lax.top_k order.
// ---------------------------------------------------------------------------
__global__ __launch_bounds__(256) void decode_kernel(
    const float* __restrict__ feat1, const float* __restrict__ feat2,
    float* __restrict__ cand, u64* __restrict__ keys) {
  const int gid = blockIdx.x * 256 + threadIdx.x;
  if (gid >= 8 * NCAND) return;
  const int b = gid / NCAND;
  const int i = gid % NCAND;
  const float* p;
  int rem, HW, W;
  float aw, ah;
  if (i < 507) {
    const int a = i / 169;
    rem = i % 169;
    HW = 169;
    W = 13;
    const float AW[3] = {81.f, 135.f, 344.f};
    const float AH[3] = {82.f, 169.f, 319.f};
    aw = AW[a];
    ah = AH[a];
    p = feat1 + ((size_t)b * 255 + a * 85) * 169 + rem;
  } else {
    const int j = i - 507;
    const int a = j / 676;
    rem = j % 676;
    HW = 676;
    W = 26;
    const float AW[3] = {10.f, 23.f, 37.f};
    const float AH[3] = {14.f, 27.f, 58.f};
    aw = AW[a];
    ah = AH[a];
    p = feat2 + ((size_t)b * 255 + a * 85) * 676 + rem;
  }
  const int gy = rem / W, gx = rem % W;
  const float invW = 1.0f / (float)W;
  float cx = (sig_(p[0]) + (float)gx) * invW;
  float cy = (sig_(p[(size_t)HW]) + (float)gy) * invW;
  float bw = expf(p[(size_t)2 * HW]) * aw / 416.0f;
  float bh = expf(p[(size_t)3 * HW]) * ah / 416.0f;
  float obj = sig_(p[(size_t)4 * HW]);
  float best = p[(size_t)5 * HW];
  int lab = 0;
  for (int c = 1; c < 80; ++c) {
    float v = p[(size_t)(5 + c) * HW];
    if (v > best) {
      best = v;
      lab = c;
    }
  }
  float cc = sig_(best);
  float score = obj * cc;
  if (score < 0.1f) score = 0.0f;
  float* o = cand + (size_t)gid * 8;
  o[0] = (cy - bh * 0.5f) * 416.0f;
  o[1] = (cx - bw * 0.5f) * 416.0f;
  o[2] = (cy + bh * 0.5f) * 416.0f;
  o[3] = (cx + bw * 0.5f) * 416.0f;
  o[4] = obj;
  o[5] = cc;
  o[6] = (float)lab;
  o[7] = score;
  keys[gid] = ((u64)__float_as_uint(score) << 32) |
              (u64)(0xFFFFFFFFu - (unsigned)i);
}

// ---------------------------------------------------------------------------
// Exact top-300 via rank (distinct keys -> bijection): sel[rank]=idx.
// Split-rank form: thread = (candidate, quarter); shfl_xor group sum.
// ---------------------------------------------------------------------------
__global__ __launch_bounds__(256) void rank_select_kernel(
    const u64* __restrict__ keys, int* __restrict__ sel) {
  const int b = blockIdx.y;
  __shared__ u64 k[NCAND];
  const u64* kb = keys + (size_t)b * NCAND;
  for (int t = threadIdx.x; t < NCAND; t += 256) k[t] = kb[t];
  __syncthreads();
  const int cand = blockIdx.x * 64 + (threadIdx.x >> 2);
  const int q = threadIdx.x & 3;
  if (cand >= NCAND) return;
  const u64 me = k[cand];
  const int jlo = q * 634;
  const int jhi = (q == 3) ? NCAND : jlo + 634;  // q=3: [1902, 2535)
  int rank = 0;
#pragma unroll 8
  for (int j = jlo; j < jhi; j++) rank += (k[j] > me) ? 1 : 0;
  rank += __shfl_xor(rank, 1, 64);
  rank += __shfl_xor(rank, 2, 64);
  if (q == 0 && rank < NKEEP) sel[b * NKEEP + rank] = cand;
}

// ---------------------------------------------------------------------------
// NMS stage 1: parallel suppression-mask build (proven round-7 form).
// ---------------------------------------------------------------------------
__global__ __launch_bounds__(256) void nms_mask_kernel(
    const float* __restrict__ cand, const int* __restrict__ sel,
    u64* __restrict__ mskg) {
  const int b = blockIdx.y;
  const int r0 = blockIdx.x * 30;
  const int tid = threadIdx.x;
  const float* cb = cand + (size_t)b * NCAND * 8;

  __shared__ float4 bxv[NKEEP];
  __shared__ int lv[NKEEP];

  for (int t = tid; t < NKEEP; t += 256) {
    const int idx = sel[b * NKEEP + t];
    const float* c = cb + (size_t)idx * 8;
    const float4 c0 = *(const float4*)c;
    const float4 c1 = *(const float4*)(c + 4);
    bxv[t] = c0;
    lv[t] = (int)c1.z | ((c1.w > 0.0f) ? 0x10000 : 0);
  }
  __syncthreads();

  if (tid >= 150) return;  // 30 rows x 5 words
  const int t = r0 + tid / 5;
  const int q = tid % 5;
  u64 w = 0;
  const int lvt = lv[t];
  if (lvt & 0x10000) {
    const float4 a = bxv[t];
    const float aarea = (a.z - a.x) * (a.w - a.y);
    const int jlo = (q * 64 > t + 1) ? q * 64 : t + 1;
    const int jhi = (q * 64 + 64 < NKEEP) ? q * 64 + 64 : NKEEP;
    for (int j = jlo; j < jhi; ++j) {
      if (lv[j] == lvt) {
        const float4 bbj = bxv[j];
        const float ty = fmaxf(a.x, bbj.x), tx = fmaxf(a.y, bbj.y);
        const float ey = fminf(a.z, bbj.z), ex = fminf(a.w, bbj.w);
        const float dy = fmaxf(ey - ty, 0.0f), dx = fmaxf(ex - tx, 0.0f);
        const float inter = dy * dx;
        const float barea = (bbj.z - bbj.x) * (bbj.w - bbj.y);
        const float iou = inter / (aarea + barea - inter + 1e-9f);
        if (iou > 0.5f) w |= 1ull << (j & 63);
      }
    }
  }
  mskg[((size_t)b * NKEEP + t) * 5 + q] = w;
}

// ---------------------------------------------------------------------------
// NMS stage 2: serial forward scan + output (proven round-7 form).
// ---------------------------------------------------------------------------
__global__ __launch_bounds__(256) void nms_scan_kernel(
    const float* __restrict__ cand, const int* __restrict__ sel,
    const u64* __restrict__ mskg, float* __restrict__ out) {
  const int b = blockIdx.x;
  const int tid = threadIdx.x;
  const float* cb = cand + (size_t)b * NCAND * 8;

  __shared__ float4 bxv[NKEEP];
  __shared__ float2 oc2[NKEEP];
  __shared__ int lv[NKEEP];
  __shared__ u64 msk[NKEEP][5];
  __shared__ u64 validw[5];
  __shared__ u64 keepw[5];

  for (int t = tid; t < NKEEP; t += 256) {
    const int idx = sel[b * NKEEP + t];
    const float* c = cb + (size_t)idx * 8;
    const float4 c0 = *(const float4*)c;
    const float4 c1 = *(const float4*)(c + 4);
    bxv[t] = c0;
    oc2[t] = make_float2(c1.x, c1.y);
    lv[t] = (int)c1.z | ((c1.w > 0.0f) ? 0x10000 : 0);
  }
  {
    const u64* mb = mskg + (size_t)b * NKEEP * 5;
    u64* md = &msk[0][0];
    for (int t = tid; t < NKEEP * 5; t += 256) md[t] = mb[t];
  }
  __syncthreads();

  {
    const u64 m1 = __ballot((lv[tid] & 0x10000) != 0);
    if ((tid & 63) == 0) validw[tid >> 6] = m1;
    const u64 m2 = __ballot(tid < 44 && (lv[tid + 256] & 0x10000) != 0);
    if (tid == 0) validw[4] = m2;
  }
  __syncthreads();

  u64 kw0 = validw[0], kw1 = validw[1], kw2 = validw[2], kw3 = validw[3],
      kw4 = validw[4];
  auto scanq = [&](u64& kwq, int q, int nb) {
    for (int bit = 0; bit < nb; ++bit) {
      const int r = q * 64 + bit;
      const u64 m = 0ull - ((kwq >> bit) & 1ull);
      kw0 &= ~(msk[r][0] & m);
      kw1 &= ~(msk[r][1] & m);
      kw2 &= ~(msk[r][2] & m);
      kw3 &= ~(msk[r][3] & m);
      kw4 &= ~(msk[r][4] & m);
    }
  };
  scanq(kw0, 0, 64);
  scanq(kw1, 1, 64);
  scanq(kw2, 2, 64);
  scanq(kw3, 3, 64);
  scanq(kw4, 4, NKEEP - 256);

  if (tid == 0) {
    keepw[0] = kw0;
    keepw[1] = kw1;
    keepw[2] = kw2;
    keepw[3] = kw3;
    keepw[4] = kw4;
  }
  __syncthreads();

  float* ob = out + (size_t)b * NKEEP * 7;
  for (int t = tid; t < NKEEP; t += 256) {
    const bool k = (keepw[t >> 6] >> (t & 63)) & 1ull;
    float* r = ob + (size_t)t * 7;
    if (k) {
      const float4 a = bxv[t];
      const float2 o2 = oc2[t];
      r[0] = a.x;
      r[1] = a.y;
      r[2] = a.z;
      r[3] = a.w;
      r[4] = o2.x;
      r[5] = o2.y;
      r[6] = (float)(lv[t] & 0xFFFF);
    } else {
      r[0] = 0.0f; r[1] = 0.0f; r[2] = 0.0f; r[3] = 0.0f;
      r[4] = 0.0f; r[5] = 0.0f; r[6] = 0.0f;
    }
  }
}

// ---------------------------------------------------------------------------
// Workspace (float offsets), lifetime-checked:
//   x1  : [0, 11075584)          x2/P(conv partials): [11075584, 16613376)
//   P3  : [5537792, 11075584)    x3p: [0, 3096576)  (dead after conv4;
//                                 conv4 prefetch overshoots to ~3102624)
//   w4r : [3200000, 3494912)  (written at conv3 launch; old-x1 dead region,
//                              below f2 start 4153344, above x3p overshoot)
//   x4p : [0, 1548288)  (written after conv4 reads x3p; conv5 prefetch
//                        overshoots ~9 KB into the dead gap below f2)
//   f2  : [4153344, 5532384)     x5 : [5532384, 6224608)
//   f1  : [6224608, 6569368)     w5r: [6224608, 7404256) (dead before f1)
//   wh2r: [7404256, 7469536)     wh1r: [7469536, 7600096)
//   Ph2 : [7600096, 10358176)
//   cd  : [6569368, 6731608)  keys: [6731608, 6772168)  sel: [6772168, 6774568)
//   mskg: [6774568, 6798568)  (u64[8*300*5]; inside dead w5r region)
// Peak = 16613376 floats = 66.5 MB.
// ---------------------------------------------------------------------------
extern "C" void kernel_launch(void* const* d_in, const int* in_sizes, int n_in,
                              void* d_out, int out_size, void* d_ws,
                              size_t ws_size, hipStream_t stream) {
  const float* images = (const float*)d_in[0];
  const float* w1 = (const float*)d_in[1];
  const float* b1 = (const float*)d_in[2];
  const float* w2 = (const float*)d_in[3];
  const float* b2 = (const float*)d_in[4];
  const float* w3 = (const float*)d_in[5];
  const float* b3 = (const float*)d_in[6];
  const float* w4 = (const float*)d_in[7];
  const float* b4 = (const float*)d_in[8];
  const float* w5 = (const float*)d_in[9];
  const float* b5 = (const float*)d_in[10];
  const float* wh1 = (const float*)d_in[11];
  const float* bh1 = (const float*)d_in[12];
  const float* wh2 = (const float*)d_in[13];
  const float* bh2 = (const float*)d_in[14];
  float* ws = (float*)d_ws;

  float* x1 = ws + 0;
  float* x2 = ws + 11075584;
  float* P3 = ws + 5537792;
  float* x3p = ws + 0;
  float* w4r = ws + 3200000;
  float* x4p = ws + 0;  // padded conv4 output, written after conv4 reads x3p
  float* f2 = ws + 4153344;
  float* x5 = ws + 5532384;
  float* f1 = ws + 6224608;
  float* cd = ws + 6569368;
  u64* keys = (u64*)(ws + 6731608);
  int* sel = (int*)(ws + 6772168);
  u64* mskg = (u64*)(ws + 6774568);
  float* P = ws + 11075584;
  float* w5r = ws + 6224608;
  float* wh2r = ws + 7404256;
  float* wh1r = ws + 7469536;
  float* Ph2 = ws + 7600096;

  // conv1: pair+z2 (1360 blocks: 4bp x 85x x 4g)
  k_conv1zp<<<1360, 256, 0, stream>>>(images, w1, b1, x1);
  // conv2: pair+z2 (704 blocks: 4bp x 22x x 8g)
  k_conv2zp<<<704, 256, 0, stream>>>(x1, w2, b2, x2);
  // conv3 pair+z2 (768) + w4 repack OCT=16 (160)
  k_conv3_repack<<<928, 256, 0, stream>>>(x2, w3, P3, w4, w4r);
  // fused conv3 reduce + bias + lrelu + zero-pad -> x3p (8*128*3024)
  k_reduce_pad3<<<12096, 256, 0, stream>>>(P3, b3, x3p);
  // conv4 z2 OCT=16 (768) + w5/wh2/wh1 repack (1024)
  k_conv4_repack<<<1792, 256, 0, stream>>>(x3p, w4r, P, w5, wh2, wh1, w5r, wh2r, wh1r);
  // fused conv4 reduce + bias + lrelu + zero-pad -> x4p (8*256*756)
  k_reduce_pad4<<<6048, 256, 0, stream>>>(P, b4, x4p);
  // conv5 z4 OCT=8 (1024) + head2 SPLIT=2 (720), both XCD-swizzled
  k_h2c5<<<1744, 256, 0, stream>>>(x4p, w5r, wh2r, P, Ph2);
  k_reduce_h2c5<<<2704 + 5388, 256, 0, stream>>>(P, Ph2, b5, bh2, x5, f2);
  // head1: split-K x16 -> 1920 blocks
  k_head1<<<dim3(1, 15, 128), 256, 0, stream>>>(x5, wh1r, P);
  reduce_bias<16, false><<<(344760 + 255) / 256, 256, 0, stream>>>(P, bh1, f1, 255, 169, 344760);

  decode_kernel<<<80, 256, 0, stream>>>(f1, f2, cd, keys);
  rank_select_kernel<<<dim3(40, 8), 256, 0, stream>>>(keys, sel);
  nms_mask_kernel<<<dim3(10, 8), 256, 0, stream>>>(cd, sel, mskg);
  nms_scan_kernel<<<8, 256, 0, stream>>>(cd, sel, mskg, (float*)d_out);
}

// Round 17
// 444.955 us; speedup vs baseline: 1.0246x; 1.0246x over previous
//
#include <hip/hip_runtime.h>
#include <stdint.h>

typedef unsigned long long u64;

__device__ __forceinline__ float sig_(float x) { return 1.0f / (1.0f + expf(-x)); }

#define NCAND 2535
#define NKEEP 300

// ---------------------------------------------------------------------------
// conv1: pair-spatial x z-paired (2 cols x 2 images), OCT=8, CIN=3, SPLIT=1,
// fused bias+lrelu (round-15 form).
// ---------------------------------------------------------------------------
__global__ __launch_bounds__(256) void k_conv1zp(
    const float* __restrict__ in, const float* __restrict__ wgt,
    const float* __restrict__ bias, float* __restrict__ out) {
  constexpr int OCT = 8, CIN = 3, HIN = 416, WIN = 416;
  constexpr int HWIN = 173056, HWOUT = 43264, WOUT = 208, COUT = 32, WP = 104;
  const int fb = blockIdx.x;  // 1360 = 4bp | 85x | 4g
  const int bp = fb & 3;
  const int r = fb >> 2;
  const int x = r % 85, g = r / 85;
  const int b0 = bp * 2;
  const int sp = x * 256 + threadIdx.x;
  if (sp >= 21632) return;  // 208 rows x 104 col-pairs
  const int oy = sp / WP, oxp = sp % WP;
  const int ox0 = oxp * 2;
  const int iy0 = oy * 2, ix0 = oxp * 4;
  const bool okY = (iy0 + 2 < HIN);
  const bool c4v = (ix0 + 4 < WIN);
  const float* inb0 = in + (size_t)b0 * CIN * HWIN + (size_t)iy0 * WIN + ix0;
  const float* inb1 = inb0 + (size_t)CIN * HWIN;
  const float* wb = wgt + (size_t)g * OCT * CIN * 9;

  float a00[OCT], a01[OCT], a10[OCT], a11[OCT];
#pragma unroll
  for (int u = 0; u < OCT; u++) {
    a00[u] = 0.0f;
    a01[u] = 0.0f;
    a10[u] = 0.0f;
    a11[u] = 0.0f;
  }

  auto load15 = [&](float v[15], const float* ip) {
#pragma unroll
    for (int ky = 0; ky < 3; ky++) {
      const bool rok = (ky < 2) || okY;
      const float* rp = ip + ky * WIN;
      float4 p = make_float4(0.f, 0.f, 0.f, 0.f);
      float c4 = 0.f;
      if (rok) {
        p = *(const float4*)rp;  // 16B-aligned: ix0%4==0, WIN%4==0
        if (c4v) c4 = rp[4];
      }
      v[ky * 5 + 0] = p.x;
      v[ky * 5 + 1] = p.y;
      v[ky * 5 + 2] = p.z;
      v[ky * 5 + 3] = p.w;
      v[ky * 5 + 4] = c4;
    }
  };
  auto fmablk4 = [&](const float v0[15], const float v1[15], int ci) {
#pragma unroll
    for (int u = 0; u < OCT; u++) {
#pragma unroll
      for (int ky = 0; ky < 3; ky++) {
#pragma unroll
        for (int kx = 0; kx < 3; kx++) {
          const float w = wb[(size_t)u * (CIN * 9) + ci * 9 + ky * 3 + kx];
          a00[u] = fmaf(v0[ky * 5 + kx], w, a00[u]);
          a01[u] = fmaf(v0[ky * 5 + kx + 2], w, a01[u]);
          a10[u] = fmaf(v1[ky * 5 + kx], w, a10[u]);
          a11[u] = fmaf(v1[ky * 5 + kx + 2], w, a11[u]);
        }
      }
    }
  };

  float vA0[15], vA1[15], vB0[15], vB1[15];
  load15(vA0, inb0);                  // ch0, img b0
  load15(vA1, inb1);                  // ch0, img b1
  load15(vB0, inb0 + HWIN);           // ch1
  load15(vB1, inb1 + HWIN);
  fmablk4(vA0, vA1, 0);
  load15(vA0, inb0 + 2 * HWIN);       // ch2 reuses ch0 buffers
  load15(vA1, inb1 + 2 * HWIN);
  fmablk4(vB0, vB1, 1);
  fmablk4(vA0, vA1, 2);

  float* ob0 =
      out + ((size_t)b0 * COUT + g * OCT) * HWOUT + (size_t)oy * WOUT + ox0;
  float* ob1 = ob0 + (size_t)COUT * HWOUT;
#pragma unroll
  for (int u = 0; u < OCT; u++) {
    const float bi = bias[g * OCT + u];
    float r00 = a00[u] + bi, r01 = a01[u] + bi;
    float r10 = a10[u] + bi, r11 = a11[u] + bi;
    r00 = r00 > 0.0f ? r00 : 0.1f * r00;
    r01 = r01 > 0.0f ? r01 : 0.1f * r01;
    r10 = r10 > 0.0f ? r10 : 0.1f * r10;
    r11 = r11 > 0.0f ? r11 : 0.1f * r11;
    *(float2*)(ob0 + (size_t)u * HWOUT) = make_float2(r00, r01);
    *(float2*)(ob1 + (size_t)u * HWOUT) = make_float2(r10, r11);
  }
}

// ---------------------------------------------------------------------------
// conv2: pair-spatial x z-paired (2 cols x 2 images), OCT=8, SPLIT=1,
// fused bias+lrelu (round-14 proven form).
// ---------------------------------------------------------------------------
__global__ __launch_bounds__(256) void k_conv2zp(
    const float* __restrict__ in, const float* __restrict__ wgt,
    const float* __restrict__ bias, float* __restrict__ out) {
  constexpr int OCT = 8, CIN = 32, HIN = 208, WIN = 208;
  constexpr int HWIN = 43264, HWOUT = 10816, WOUT = 104, COUT = 64, WP = 52;
  const int fb = blockIdx.x;  // 704 = 4bp | 22x | 8g
  const int bp = fb & 3;
  const int r = fb >> 2;
  const int x = r % 22, g = r / 22;
  const int b0 = bp * 2;
  const int sp = x * 256 + threadIdx.x;
  if (sp >= 5408) return;  // 104 rows x 52 col-pairs
  const int oy = sp / WP, oxp = sp % WP;
  const int ox0 = oxp * 2;
  const int iy0 = oy * 2, ix0 = oxp * 4;
  const bool okY = (iy0 + 2 < HIN);
  const bool c4v = (ix0 + 4 < WIN);
  const float* inb0 = in + (size_t)b0 * CIN * HWIN + (size_t)iy0 * WIN + ix0;
  const float* inb1 = inb0 + (size_t)CIN * HWIN;
  const float* wb = wgt + (size_t)g * OCT * CIN * 9;

  float a00[OCT], a01[OCT], a10[OCT], a11[OCT];
#pragma unroll
  for (int u = 0; u < OCT; u++) {
    a00[u] = 0.0f;
    a01[u] = 0.0f;
    a10[u] = 0.0f;
    a11[u] = 0.0f;
  }

  auto load15 = [&](float v[15], const float* ip) {
#pragma unroll
    for (int ky = 0; ky < 3; ky++) {
      const bool rok = (ky < 2) || okY;
      const float* rp = ip + ky * WIN;
      float4 p = make_float4(0.f, 0.f, 0.f, 0.f);
      float c4 = 0.f;
      if (rok) {
        p = *(const float4*)rp;  // 16B-aligned: ix0%4==0, WIN%4==0
        if (c4v) c4 = rp[4];
      }
      v[ky * 5 + 0] = p.x;
      v[ky * 5 + 1] = p.y;
      v[ky * 5 + 2] = p.z;
      v[ky * 5 + 3] = p.w;
      v[ky * 5 + 4] = c4;
    }
  };
  auto fmablk4 = [&](const float v0[15], const float v1[15], int ci) {
#pragma unroll
    for (int u = 0; u < OCT; u++) {
#pragma unroll
      for (int ky = 0; ky < 3; ky++) {
#pragma unroll
        for (int kx = 0; kx < 3; kx++) {
          const float w = wb[(size_t)u * (CIN * 9) + ci * 9 + ky * 3 + kx];
          a00[u] = fmaf(v0[ky * 5 + kx], w, a00[u]);
          a01[u] = fmaf(v0[ky * 5 + kx + 2], w, a01[u]);
          a10[u] = fmaf(v1[ky * 5 + kx], w, a10[u]);
          a11[u] = fmaf(v1[ky * 5 + kx + 2], w, a11[u]);
        }
      }
    }
  };

  float vA0[15], vA1[15], vB0[15], vB1[15];
  load15(vA0, inb0);
  load15(vA1, inb1);
#pragma unroll 1
  for (int ci = 0; ci < CIN; ci += 2) {
    const int cn = (ci + 2) & (CIN - 1);  // clamp final overshoot (wraps)
    load15(vB0, inb0 + (size_t)(ci + 1) * HWIN);
    load15(vB1, inb1 + (size_t)(ci + 1) * HWIN);
    fmablk4(vA0, vA1, ci);
    load15(vA0, inb0 + (size_t)cn * HWIN);
    load15(vA1, inb1 + (size_t)cn * HWIN);
    fmablk4(vB0, vB1, ci + 1);
  }

  float* ob0 =
      out + ((size_t)b0 * COUT + g * OCT) * HWOUT + (size_t)oy * WOUT + ox0;
  float* ob1 = ob0 + (size_t)COUT * HWOUT;
#pragma unroll
  for (int u = 0; u < OCT; u++) {
    const float bi = bias[g * OCT + u];
    float r00 = a00[u] + bi, r01 = a01[u] + bi;
    float r10 = a10[u] + bi, r11 = a11[u] + bi;
    r00 = r00 > 0.0f ? r00 : 0.1f * r00;
    r01 = r01 > 0.0f ? r01 : 0.1f * r01;
    r10 = r10 > 0.0f ? r10 : 0.1f * r10;
    r11 = r11 > 0.0f ? r11 : 0.1f * r11;
    *(float2*)(ob0 + (size_t)u * HWOUT) = make_float2(r00, r01);
    *(float2*)(ob1 + (size_t)u * HWOUT) = make_float2(r10, r11);
  }
}

// ---------------------------------------------------------------------------
// conv3: pair-spatial x z-paired (2 cols x 2 images), OCT=8, SPLIT=2.
// + w4 repack tail for conv4z2 OCT=16:
//   w4r[(g*4+s)*4608 + (cl*16+u)*9 + k], g in [0,16), u in [0,16).
// ---------------------------------------------------------------------------
__global__ __launch_bounds__(256) void k_conv3_repack(
    const float* __restrict__ in, const float* __restrict__ wgt,
    float* __restrict__ P3, const float* __restrict__ w4,
    float* __restrict__ w4r) {
  const int fb = blockIdx.x;
  if (fb < 768) {  // 8(s,bp) * 6x * 16g
    constexpr int OCT = 8, CS = 32, HIN = 104, WIN = 104;
    constexpr int HWIN = 10816, HWOUT = 2704, WOUT = 52, COUT = 128, WP = 26;
    const int low3 = fb & 7;  // s*4 + bp (XCD affinity)
    const int s = low3 >> 2, bp = low3 & 3;
    const int r = fb >> 3;
    const int x = r % 6, g = r / 6;
    const int b0 = bp * 2;
    const int sp = x * 256 + threadIdx.x;
    if (sp >= 1352) return;  // 52 rows x 26 col-pairs
    const int oy = sp / WP, oxp = sp % WP;
    const int ox0 = oxp * 2;
    const int iy0 = oy * 2, ix0 = oxp * 4;
    const bool okY = (iy0 + 2 < HIN);
    const bool c4v = (ix0 + 4 < WIN);
    const float* inb0 =
        in + ((size_t)b0 * 64 + s * CS) * HWIN + (size_t)iy0 * WIN + ix0;
    const float* inb1 = inb0 + (size_t)64 * HWIN;
    const float* wb = wgt + ((size_t)(g * OCT) * 64 + s * CS) * 9;

    float a00[OCT], a01[OCT], a10[OCT], a11[OCT];
#pragma unroll
    for (int u = 0; u < OCT; u++) {
      a00[u] = 0.0f;
      a01[u] = 0.0f;
      a10[u] = 0.0f;
      a11[u] = 0.0f;
    }

    auto load15 = [&](float v[15], const float* ip) {
#pragma unroll
      for (int ky = 0; ky < 3; ky++) {
        const bool rok = (ky < 2) || okY;
        const float* rp = ip + ky * WIN;
        float4 p = make_float4(0.f, 0.f, 0.f, 0.f);
        float c4 = 0.f;
        if (rok) {
          p = *(const float4*)rp;  // 16B-aligned: ix0%4==0, WIN%4==0
          if (c4v) c4 = rp[4];
        }
        v[ky * 5 + 0] = p.x;
        v[ky * 5 + 1] = p.y;
        v[ky * 5 + 2] = p.z;
        v[ky * 5 + 3] = p.w;
        v[ky * 5 + 4] = c4;
      }
    };
    auto fmablk4 = [&](const float v0[15], const float v1[15], int ci) {
#pragma unroll
      for (int u = 0; u < OCT; u++) {
#pragma unroll
        for (int ky = 0; ky < 3; ky++) {
#pragma unroll
          for (int kx = 0; kx < 3; kx++) {
            const float w = wb[(size_t)u * (64 * 9) + ci * 9 + ky * 3 + kx];
            a00[u] = fmaf(v0[ky * 5 + kx], w, a00[u]);
            a01[u] = fmaf(v0[ky * 5 + kx + 2], w, a01[u]);
            a10[u] = fmaf(v1[ky * 5 + kx], w, a10[u]);
            a11[u] = fmaf(v1[ky * 5 + kx + 2], w, a11[u]);
          }
        }
      }
    };

    float vA0[15], vA1[15], vB0[15], vB1[15];
    load15(vA0, inb0);
    load15(vA1, inb1);
#pragma unroll 1
    for (int ci = 0; ci < CS; ci += 2) {
      const int cn = (ci + 2) & (CS - 1);  // clamp final overshoot (wraps)
      load15(vB0, inb0 + (size_t)(ci + 1) * HWIN);
      load15(vB1, inb1 + (size_t)(ci + 1) * HWIN);
      fmablk4(vA0, vA1, ci);
      load15(vA0, inb0 + (size_t)cn * HWIN);
      load15(vA1, inb1 + (size_t)cn * HWIN);
      fmablk4(vB0, vB1, ci + 1);
    }

    float* ob0 =
        P3 + ((size_t)(s * 8 + b0) * COUT + g * OCT) * HWOUT +
        (size_t)oy * WOUT + ox0;
    float* ob1 = ob0 + (size_t)COUT * HWOUT;  // image b0+1, same s-slice
#pragma unroll
    for (int u = 0; u < OCT; u++) {
      *(float2*)(ob0 + (size_t)u * HWOUT) = make_float2(a00[u], a01[u]);
      *(float2*)(ob1 + (size_t)u * HWOUT) = make_float2(a10[u], a11[u]);
    }
    return;
  }
  const int base = (fb - 768) * 256 + threadIdx.x;
  for (int gid = base; gid < 294912; gid += 160 * 256) {
    const int oc = gid / (128 * 9), r = gid % (128 * 9);
    const int ci = r / 9, k = r % 9;
    const int g = oc / 16, u = oc % 16, s = ci / 32, cl = ci % 32;
    w4r[(size_t)(g * 4 + s) * 4608 + (cl * 16 + u) * 9 + k] = w4[gid];
  }
}

// ---------------------------------------------------------------------------
// Fused conv3 reduce + bias + lrelu + ZERO-PAD to 54 rows x 56 cols stride.
// x3p[(b*128+oc)*3024 + y*56 + x], rows/cols >= 52 are 0.
// ---------------------------------------------------------------------------
__global__ __launch_bounds__(256) void k_reduce_pad3(
    const float* __restrict__ P3, const float* __restrict__ bias,
    float* __restrict__ x3p) {
  const int gid = blockIdx.x * 256 + threadIdx.x;
  if (gid >= 8 * 128 * 3024) return;
  const int c = gid / 3024;  // b*128 + oc
  const int r = gid % 3024;
  const int y = r / 56, x = r % 56;
  float a = 0.0f;
  if (y < 52 && x < 52) {
    const int src = c * 2704 + y * 52 + x;
    a = P3[src] + P3[2768896 + src];
    a += bias[c & 127];
    a = a > 0.0f ? a : 0.1f * a;
  }
  x3p[gid] = a;
}

// ---------------------------------------------------------------------------
// conv4: z-paired OCT=16 single-spatial (round-12 form).
// ---------------------------------------------------------------------------
__device__ __forceinline__ void conv4z2_body(const float* __restrict__ in,
                                             const float* __restrict__ wgt,
                                             float* __restrict__ out, int g,
                                             int s, int bp, int x) {
  constexpr int OCT = 16, CS = 32;
  constexpr int PHW = 3024, PW = 56;  // padded 54x56-stride plane
  constexpr int HWOUT = 676, WOUT = 26, COUT = 256;
  const int b0 = bp * 2;
  const int sp = x * 256 + threadIdx.x;
  if (sp >= HWOUT) return;
  const int oy = sp / WOUT, ox = sp % WOUT;
  const float* inb0 =
      in + ((size_t)b0 * 128 + s * CS) * PHW + (size_t)(oy * 2) * PW + ox * 2;
  const float* inb1 = inb0 + (size_t)128 * PHW;  // b1 = b0+1
  const float* wb = wgt + (size_t)(g * 4 + s) * 4608;

  float acc0[OCT], acc1[OCT];
#pragma unroll
  for (int u = 0; u < OCT; u++) {
    acc0[u] = 0.0f;
    acc1[u] = 0.0f;
  }

  auto load9 = [&](float v[9], const float* ip) {
#pragma unroll
    for (int ky = 0; ky < 3; ky++) {
      const float2 p = *(const float2*)(ip + ky * PW);
      v[ky * 3 + 0] = p.x;
      v[ky * 3 + 1] = p.y;
      v[ky * 3 + 2] = ip[ky * PW + 2];
    }
  };
  auto fmablk2 = [&](const float v0[9], const float v1[9], int ci) {
#pragma unroll
    for (int u = 0; u < OCT; u++) {
#pragma unroll
      for (int k = 0; k < 9; k++) {
        const float w = wb[(size_t)(ci * OCT + u) * 9 + k];
        acc0[u] = fmaf(v0[k], w, acc0[u]);
        acc1[u] = fmaf(v1[k], w, acc1[u]);
      }
    }
  };

  float vA0[9], vA1[9], vB0[9], vB1[9];
  load9(vA0, inb0);
  load9(vA1, inb1);
#pragma unroll 1
  for (int ci = 0; ci < CS; ci += 2) {
    // prefetch next channel for both planes. Final overshoot reads stay
    // inside the workspace (values unused; w4r sits above the overshoot).
    load9(vB0, inb0 + (size_t)(ci + 1) * PHW);
    load9(vB1, inb1 + (size_t)(ci + 1) * PHW);
    fmablk2(vA0, vA1, ci);
    load9(vA0, inb0 + (size_t)(ci + 2) * PHW);
    load9(vA1, inb1 + (size_t)(ci + 2) * PHW);
    fmablk2(vB0, vB1, ci + 1);
  }

  float* ob0 = out + ((size_t)(s * 8 + b0) * COUT + g * OCT) * HWOUT + sp;
  float* ob1 = ob0 + (size_t)COUT * HWOUT;  // b1 slice
#pragma unroll
  for (int u = 0; u < OCT; u++) {
    ob0[(size_t)u * HWOUT] = acc0[u];
    ob1[(size_t)u * HWOUT] = acc1[u];
  }
}

// ---------------------------------------------------------------------------
// conv4z2 OCT=16 (768 blocks: 16(bp,s) x 3x x 16g, XCD-swizzled low bits) +
// grid-stride repack (1024 blocks) of w5 (OCT=16 layout) / wh2 / wh1.
// ---------------------------------------------------------------------------
__global__ __launch_bounds__(256) void k_conv4_repack(
    const float* __restrict__ x3p, const float* __restrict__ w4r,
    float* __restrict__ P, const float* __restrict__ w5,
    const float* __restrict__ wh2, const float* __restrict__ wh1,
    float* __restrict__ w5r, float* __restrict__ wh2r,
    float* __restrict__ wh1r) {
  const int fb = blockIdx.x;
  if (fb < 768) {
    const int low4 = fb & 15;  // bp*4 + s
    const int bp = low4 >> 2, s = low4 & 3;
    const int r = fb >> 4;  // [0,48)
    const int x = r % 3, g = r / 3;
    conv4z2_body(x3p, w4r, P, g, s, bp, x);
    return;
  }
  const int base = (fb - 768) * 256 + threadIdx.x;
  for (int gid = base; gid < 1375488; gid += 1024 * 256) {
    if (gid < 1179648) {  // w5: COUT=512, CIN=256, CS=32, OCT=16 (round-3
      const int oc = gid / (256 * 9), r = gid % (256 * 9);  // proven layout)
      const int ci = r / 9, k = r % 9;
      const int g = oc / 16, u = oc % 16, s = ci / 32, cl = ci % 32;
      w5r[(((size_t)(g * 8 + s) * 32 + cl) * 16 + u) * 9 + k] = w5[gid];
    } else if (gid < 1179648 + 65280) {  // wh2: 255x256, SPLIT=2 -> CS=128
      const int t = gid - 1179648;
      const int oc = t / 256, ci = t % 256;
      const int g = oc / 17, u = oc % 17, s = ci / 128, cl = ci % 128;
      wh2r[((size_t)(g * 2 + s) * 128 + cl) * 17 + u] = wh2[t];
    } else {  // wh1: 255x512, SPLIT=16 -> CS=32
      const int t = gid - 1179648 - 65280;
      const int oc = t / 512, ci = t % 512;
      const int g = oc / 17, u = oc % 17, s = ci / 32, cl = ci % 32;
      wh1r[((size_t)(g * 16 + s) * 32 + cl) * 17 + u] = wh1[t];
    }
  }
}

// ---------------------------------------------------------------------------
// Fused conv4 reduce + bias + lrelu + ZERO-PAD to 27 rows x 28 cols stride.
// x4p[(b*256+oc)*756 + y*28 + x], rows/cols >= 26 are 0.
// ---------------------------------------------------------------------------
__global__ __launch_bounds__(256) void k_reduce_pad4(
    const float* __restrict__ P, const float* __restrict__ bias,
    float* __restrict__ x4p) {
  const int gid = blockIdx.x * 256 + threadIdx.x;
  if (gid >= 8 * 256 * 756) return;
  const int c = gid / 756;  // b*256 + oc
  const int r = gid % 756;
  const int y = r / 28, x = r % 28;
  float a = 0.0f;
  if (y < 26 && x < 26) {
    const int src = c * 676 + y * 26 + x;
#pragma unroll
    for (int s = 0; s < 4; s++) a += P[(size_t)s * 1384448 + src];
    a += bias[c & 255];
    a = a > 0.0f ? a : 0.1f * a;
  }
  x4p[gid] = a;
}

// ---------------------------------------------------------------------------
// 1x1 head body; PAD=true reads the 27x28-stride padded x4p plane.
// ---------------------------------------------------------------------------
template <int CIN, int OCT, int SPLIT, bool PAD>
__device__ __forceinline__ void head_body(const float* __restrict__ in,
                                          const float* __restrict__ wgt,
                                          float* __restrict__ out, int HW,
                                          int bx, int g, int bz) {
  constexpr int CS = CIN / SPLIT;  // multiple of 8
  const int sp = bx * 256 + threadIdx.x;
  if (sp >= HW) return;
  const int oc0 = g * OCT;
  const int b = bz / SPLIT, s = bz % SPLIT;
  const int IHW = PAD ? 756 : HW;
  const int psp = PAD ? (sp / 26) * 28 + (sp % 26) : sp;
  const float* ip = in + ((size_t)b * CIN + s * CS) * IHW + psp;
  const float* wb = wgt + (size_t)(g * SPLIT + s) * CS * OCT;
  float acc[OCT];
#pragma unroll
  for (int u = 0; u < OCT; u++) acc[u] = 0.0f;

  auto fma4 = [&](const float v[4], int base) {
#pragma unroll
    for (int j = 0; j < 4; j++) {
#pragma unroll
      for (int u = 0; u < OCT; u++)
        acc[u] = fmaf(v[j], wb[(size_t)(base + j) * OCT + u], acc[u]);
    }
  };

  float vA[4], vB[4];
#pragma unroll
  for (int j = 0; j < 4; j++) {
    vA[j] = ip[(size_t)j * IHW];
    vB[j] = ip[(size_t)(4 + j) * IHW];
  }
  for (int c0 = 0; c0 < CS; c0 += 8) {
    float nA[4];
    if (c0 + 8 < CS) {
#pragma unroll
      for (int j = 0; j < 4; j++) nA[j] = ip[(size_t)(c0 + 8 + j) * IHW];
    }
    fma4(vA, c0);
    float nB[4];
    if (c0 + 12 < CS) {
#pragma unroll
      for (int j = 0; j < 4; j++) nB[j] = ip[(size_t)(c0 + 12 + j) * IHW];
    }
    fma4(vB, c0 + 4);
    if (c0 + 8 < CS) {
#pragma unroll
      for (int j = 0; j < 4; j++) vA[j] = nA[j];
    }
    if (c0 + 12 < CS) {
#pragma unroll
      for (int j = 0; j < 4; j++) vB[j] = nB[j];
    }
  }
#pragma unroll
  for (int u = 0; u < OCT; u++)
    out[((size_t)(s * 8 + b) * 255 + oc0 + u) * HW + sp] = acc[u];
}

// ---------------------------------------------------------------------------
// conv5: z-paired OCT=16 (round-12 proven form; w5r layout proven round 3).
// ---------------------------------------------------------------------------
__device__ __forceinline__ void conv5z2_body(const float* __restrict__ in,
                                             const float* __restrict__ wgt,
                                             float* __restrict__ out, int g,
                                             int s, int bp) {
  constexpr int OCT = 16, CS = 32;
  constexpr int PHW = 756, PW = 28;  // padded 27x28-stride plane
  constexpr int HWOUT = 169, WOUT = 13, COUT = 512;
  const int b0 = bp * 2;
  const int sp = threadIdx.x;
  if (sp >= HWOUT) return;
  const int oy = sp / WOUT, ox = sp % WOUT;
  const float* inb0 =
      in + ((size_t)b0 * 256 + s * CS) * PHW + (size_t)(oy * 2) * PW + ox * 2;
  const float* inb1 = inb0 + (size_t)256 * PHW;  // b1 = b0+1
  const float* wb = wgt + (size_t)(g * 8 + s) * 4608;

  float acc0[OCT], acc1[OCT];
#pragma unroll
  for (int u = 0; u < OCT; u++) {
    acc0[u] = 0.0f;
    acc1[u] = 0.0f;
  }

  auto load9 = [&](float v[9], const float* ip) {
#pragma unroll
    for (int ky = 0; ky < 3; ky++) {
      const float2 p = *(const float2*)(ip + ky * PW);
      v[ky * 3 + 0] = p.x;
      v[ky * 3 + 1] = p.y;
      v[ky * 3 + 2] = ip[ky * PW + 2];
    }
  };
  auto fmablk2 = [&](const float v0[9], const float v1[9], int ci) {
#pragma unroll
    for (int u = 0; u < OCT; u++) {
#pragma unroll
      for (int k = 0; k < 9; k++) {
        const float w = wb[(size_t)(ci * OCT + u) * 9 + k];
        acc0[u] = fmaf(v0[k], w, acc0[u]);
        acc1[u] = fmaf(v1[k], w, acc1[u]);
      }
    }
  };

  float vA0[9], vA1[9], vB0[9], vB1[9];
  load9(vA0, inb0);
  load9(vA1, inb1);
#pragma unroll 1
  for (int ci = 0; ci < CS; ci += 2) {
    // Final overshoot (~2 planes past x4p) lands in the dead gap below f2.
    load9(vB0, inb0 + (size_t)(ci + 1) * PHW);
    load9(vB1, inb1 + (size_t)(ci + 1) * PHW);
    fmablk2(vA0, vA1, ci);
    load9(vA0, inb0 + (size_t)(ci + 2) * PHW);
    load9(vA1, inb1 + (size_t)(ci + 2) * PHW);
    fmablk2(vB0, vB1, ci + 1);
  }

  float* ob0 = out + ((size_t)(s * 8 + b0) * COUT + g * OCT) * HWOUT + sp;
  float* ob1 = ob0 + (size_t)COUT * HWOUT;  // b1 slice
#pragma unroll
  for (int u = 0; u < OCT; u++) {
    ob0[(size_t)u * HWOUT] = acc0[u];
    ob1[(size_t)u * HWOUT] = acc1[u];
  }
}

// ---------------------------------------------------------------------------
// Merged launch, XCD-swizzled: conv5 fb<1024 (fb%8 == s; 4bp x 32g);
// head2 blocks 1024..1743 (id%8 == z'%8).
// ---------------------------------------------------------------------------
__global__ __launch_bounds__(256) void k_h2c5(const float* __restrict__ x4p,
                                              const float* __restrict__ w5r,
                                              const float* __restrict__ wh2r,
                                              float* __restrict__ P5,
                                              float* __restrict__ Ph2) {
  const int fb = blockIdx.x;
  if (fb < 1024) {  // 8s * 4bp * 32g
    const int s = fb & 7;
    const int r = fb >> 3;
    const int bp = r & 3;
    const int g = r >> 2;
    conv5z2_body(x4p, w5r, P5, g, s, bp);
  } else {
    const int id = fb - 1024;  // 720 = 8 * 3x * 2zhi * 15g
    const int low3 = id & 7;
    int r = id >> 3;
    const int x = r % 3;
    r /= 3;
    const int zhi = r & 1;
    const int g = r >> 1;
    head_body<256, 17, 2, true>(x4p, wh2r, Ph2, 676, x, g, low3 + 8 * zhi);
  }
}

__global__ __launch_bounds__(256) void k_head1(const float* __restrict__ i,
                                               const float* __restrict__ w,
                                               float* __restrict__ o) {
  head_body<512, 17, 16, false>(i, w, o, 169, blockIdx.x, blockIdx.y,
                                blockIdx.z);
}

// ---------------------------------------------------------------------------
// Reduce SPLIT partials (slice-major, deterministic) + bias (+ lrelu).
// ---------------------------------------------------------------------------
template <int SPLIT, bool LRELU>
__device__ __forceinline__ void reduce_body(const float* __restrict__ P,
                                            const float* __restrict__ bias,
                                            float* __restrict__ out, int COUT,
                                            int HWOUT, int N, int gid) {
  if (gid >= N) return;
  float a = 0.0f;
#pragma unroll
  for (int s = 0; s < SPLIT; s++) a += P[(size_t)s * N + gid];
  const int oc = (gid / HWOUT) % COUT;
  a += bias[oc];
  if (LRELU) a = a > 0.0f ? a : 0.1f * a;
  out[gid] = a;
}

template <int SPLIT, bool LRELU>
__global__ __launch_bounds__(256) void reduce_bias(
    const float* __restrict__ P, const float* __restrict__ bias,
    float* __restrict__ out, int COUT, int HWOUT, int N) {
  reduce_body<SPLIT, LRELU>(P, bias, out, COUT, HWOUT, N,
                            blockIdx.x * 256 + threadIdx.x);
}

// Merged reduce for conv5 (SPLIT=8, lrelu -> x5) + head2 (SPLIT=2 -> f2).
__global__ __launch_bounds__(256) void k_reduce_h2c5(
    const float* __restrict__ P5, const float* __restrict__ Ph2,
    const float* __restrict__ b5, const float* __restrict__ bh2,
    float* __restrict__ x5, float* __restrict__ f2) {
  const int fb = blockIdx.x;
  if (fb < 2704) {
    reduce_body<8, true>(P5, b5, x5, 512, 169, 692224,
                         fb * 256 + threadIdx.x);
  } else {
    reduce_body<2, false>(Ph2, bh2, f2, 255, 676, 1379040,
                          (fb - 2704) * 256 + threadIdx.x);
  }
}

// ---------------------------------------------------------------------------
// Decode both heads -> cand[b][i][8] = {y1,x1,y2,x2,obj,cc,label,score} and
// packed keys (score_bits<<32)|(0xFFFFFFFF-i) matching jax.lax.top_k order.
// ---------------------------------------------------------------------------
__global__ __launch_bounds__(256) void decode_kernel(
    const float* __restrict__ feat1, const float* __restrict__ feat2,
    float* __restrict__ cand, u64* __restrict__ keys) {
  const int gid = blockIdx.x * 256 + threadIdx.x;
  if (gid >= 8 * NCAND) return;
  const int b = gid / NCAND;
  const int i = gid % NCAND;
  const float* p;
  int rem, HW, W;
  float aw, ah;
  if (i < 507) {
    const int a = i / 169;
    rem = i % 169;
    HW = 169;
    W = 13;
    const float AW[3] = {81.f, 135.f, 344.f};
    const float AH[3] = {82.f, 169.f, 319.f};
    aw = AW[a];
    ah = AH[a];
    p = feat1 + ((size_t)b * 255 + a * 85) * 169 + rem;
  } else {
    const int j = i - 507;
    const int a = j / 676;
    rem = j % 676;
    HW = 676;
    W = 26;
    const float AW[3] = {10.f, 23.f, 37.f};
    const float AH[3] = {14.f, 27.f, 58.f};
    aw = AW[a];
    ah = AH[a];
    p = feat2 + ((size_t)b * 255 + a * 85) * 676 + rem;
  }
  const int gy = rem / W, gx = rem % W;
  const float invW = 1.0f / (float)W;
  float cx = (sig_(p[0]) + (float)gx) * invW;
  float cy = (sig_(p[(size_t)HW]) + (float)gy) * invW;
  float bw = expf(p[(size_t)2 * HW]) * aw / 416.0f;
  float bh = expf(p[(size_t)3 * HW]) * ah / 416.0f;
  float obj = sig_(p[(size_t)4 * HW]);
  float best = p[(size_t)5 * HW];
  int lab = 0;
  for (int c = 1; c < 80; ++c) {
    float v = p[(size_t)(5 + c) * HW];
    if (v > best) {
      best = v;
      lab = c;
    }
  }
  float cc = sig_(best);
  float score = obj * cc;
  if (score < 0.1f) score = 0.0f;
  float* o = cand + (size_t)gid * 8;
  o[0] = (cy - bh * 0.5f) * 416.0f;
  o[1] = (cx - bw * 0.5f) * 416.0f;
  o[2] = (cy + bh * 0.5f) * 416.0f;
  o[3] = (cx + bw * 0.5f) * 416.0f;
  o[4] = obj;
  o[5] = cc;
  o[6] = (float)lab;
  o[7] = score;
  keys[gid] = ((u64)__float_as_uint(score) << 32) |
              (u64)(0xFFFFFFFFu - (unsigned)i);
}

// ---------------------------------------------------------------------------
// Exact top-300 via rank (distinct keys -> bijection): sel[rank]=idx.
// Split-rank form: thread = (candidate, quarter); shfl_xor group sum.
// ---------------------------------------------------------------------------
__global__ __launch_bounds__(256) void rank_select_kernel(
    const u64* __restrict__ keys, int* __restrict__ sel) {
  const int b = blockIdx.y;
  __shared__ u64 k[NCAND];
  const u64* kb = keys + (size_t)b * NCAND;
  for (int t = threadIdx.x; t < NCAND; t += 256) k[t] = kb[t];
  __syncthreads();
  const int cand = blockIdx.x * 64 + (threadIdx.x >> 2);
  const int q = threadIdx.x & 3;
  if (cand >= NCAND) return;
  const u64 me = k[cand];
  const int jlo = q * 634;
  const int jhi = (q == 3) ? NCAND : jlo + 634;  // q=3: [1902, 2535)
  int rank = 0;
#pragma unroll 8
  for (int j = jlo; j < jhi; j++) rank += (k[j] > me) ? 1 : 0;
  rank += __shfl_xor(rank, 1, 64);
  rank += __shfl_xor(rank, 2, 64);
  if (q == 0 && rank < NKEEP) sel[b * NKEEP + rank] = cand;
}

// ---------------------------------------------------------------------------
// NMS stage 1: parallel suppression-mask build (proven round-7 form).
// ---------------------------------------------------------------------------
__global__ __launch_bounds__(256) void nms_mask_kernel(
    const float* __restrict__ cand, const int* __restrict__ sel,
    u64* __restrict__ mskg) {
  const int b = blockIdx.y;
  const int r0 = blockIdx.x * 30;
  const int tid = threadIdx.x;
  const float* cb = cand + (size_t)b * NCAND * 8;

  __shared__ float4 bxv[NKEEP];
  __shared__ int lv[NKEEP];

  for (int t = tid; t < NKEEP; t += 256) {
    const int idx = sel[b * NKEEP + t];
    const float* c = cb + (size_t)idx * 8;
    const float4 c0 = *(const float4*)c;
    const float4 c1 = *(const float4*)(c + 4);
    bxv[t] = c0;
    lv[t] = (int)c1.z | ((c1.w > 0.0f) ? 0x10000 : 0);
  }
  __syncthreads();

  if (tid >= 150) return;  // 30 rows x 5 words
  const int t = r0 + tid / 5;
  const int q = tid % 5;
  u64 w = 0;
  const int lvt = lv[t];
  if (lvt & 0x10000) {
    const float4 a = bxv[t];
    const float aarea = (a.z - a.x) * (a.w - a.y);
    const int jlo = (q * 64 > t + 1) ? q * 64 : t + 1;
    const int jhi = (q * 64 + 64 < NKEEP) ? q * 64 + 64 : NKEEP;
    for (int j = jlo; j < jhi; ++j) {
      if (lv[j] == lvt) {
        const float4 bbj = bxv[j];
        const float ty = fmaxf(a.x, bbj.x), tx = fmaxf(a.y, bbj.y);
        const float ey = fminf(a.z, bbj.z), ex = fminf(a.w, bbj.w);
        const float dy = fmaxf(ey - ty, 0.0f), dx = fmaxf(ex - tx, 0.0f);
        const float inter = dy * dx;
        const float barea = (bbj.z - bbj.x) * (bbj.w - bbj.y);
        const float iou = inter / (aarea + barea - inter + 1e-9f);
        if (iou > 0.5f) w |= 1ull << (j & 63);
      }
    }
  }
  mskg[((size_t)b * NKEEP + t) * 5 + q] = w;
}

// ---------------------------------------------------------------------------
// NMS stage 2: serial forward scan + output (proven round-7 form).
// ---------------------------------------------------------------------------
__global__ __launch_bounds__(256) void nms_scan_kernel(
    const float* __restrict__ cand, const int* __restrict__ sel,
    const u64* __restrict__ mskg, float* __restrict__ out) {
  const int b = blockIdx.x;
  const int tid = threadIdx.x;
  const float* cb = cand + (size_t)b * NCAND * 8;

  __shared__ float4 bxv[NKEEP];
  __shared__ float2 oc2[NKEEP];
  __shared__ int lv[NKEEP];
  __shared__ u64 msk[NKEEP][5];
  __shared__ u64 validw[5];
  __shared__ u64 keepw[5];

  for (int t = tid; t < NKEEP; t += 256) {
    const int idx = sel[b * NKEEP + t];
    const float* c = cb + (size_t)idx * 8;
    const float4 c0 = *(const float4*)c;
    const float4 c1 = *(const float4*)(c + 4);
    bxv[t] = c0;
    oc2[t] = make_float2(c1.x, c1.y);
    lv[t] = (int)c1.z | ((c1.w > 0.0f) ? 0x10000 : 0);
  }
  {
    const u64* mb = mskg + (size_t)b * NKEEP * 5;
    u64* md = &msk[0][0];
    for (int t = tid; t < NKEEP * 5; t += 256) md[t] = mb[t];
  }
  __syncthreads();

  {
    const u64 m1 = __ballot((lv[tid] & 0x10000) != 0);
    if ((tid & 63) == 0) validw[tid >> 6] = m1;
    const u64 m2 = __ballot(tid < 44 && (lv[tid + 256] & 0x10000) != 0);
    if (tid == 0) validw[4] = m2;
  }
  __syncthreads();

  u64 kw0 = validw[0], kw1 = validw[1], kw2 = validw[2], kw3 = validw[3],
      kw4 = validw[4];
  auto scanq = [&](u64& kwq, int q, int nb) {
    for (int bit = 0; bit < nb; ++bit) {
      const int r = q * 64 + bit;
      const u64 m = 0ull - ((kwq >> bit) & 1ull);
      kw0 &= ~(msk[r][0] & m);
      kw1 &= ~(msk[r][1] & m);
      kw2 &= ~(msk[r][2] & m);
      kw3 &= ~(msk[r][3] & m);
      kw4 &= ~(msk[r][4] & m);
    }
  };
  scanq(kw0, 0, 64);
  scanq(kw1, 1, 64);
  scanq(kw2, 2, 64);
  scanq(kw3, 3, 64);
  scanq(kw4, 4, NKEEP - 256);

  if (tid == 0) {
    keepw[0] = kw0;
    keepw[1] = kw1;
    keepw[2] = kw2;
    keepw[3] = kw3;
    keepw[4] = kw4;
  }
  __syncthreads();

  float* ob = out + (size_t)b * NKEEP * 7;
  for (int t = tid; t < NKEEP; t += 256) {
    const bool k = (keepw[t >> 6] >> (t & 63)) & 1ull;
    float* r = ob + (size_t)t * 7;
    if (k) {
      const float4 a = bxv[t];
      const float2 o2 = oc2[t];
      r[0] = a.x;
      r[1] = a.y;
      r[2] = a.z;
      r[3] = a.w;
      r[4] = o2.x;
      r[5] = o2.y;
      r[6] = (float)(lv[t] & 0xFFFF);
    } else {
      r[0] = 0.0f; r[1] = 0.0f; r[2] = 0.0f; r[3] = 0.0f;
      r[4] = 0.0f; r[5] = 0.0f; r[6] = 0.0f;
    }
  }
}

// ---------------------------------------------------------------------------
// Workspace (float offsets), lifetime-checked:
//   x1  : [0, 11075584)          x2/P(conv partials): [11075584, 16613376)
//   P3  : [5537792, 11075584)    x3p: [0, 3096576)  (dead after conv4;
//                                 conv4 prefetch overshoots to ~3102624)
//   w4r : [3200000, 3494912)  (written at conv3 launch; old-x1 dead region,
//                              below f2 start 4153344, above x3p overshoot)
//   x4p : [0, 1548288)  (written after conv4 reads x3p; conv5 prefetch
//                        overshoots ~6 KB into the dead gap below f2)
//   f2  : [4153344, 5532384)     x5 : [5532384, 6224608)
//   f1  : [6224608, 6569368)     w5r: [6224608, 7404256) (dead before f1)
//   wh2r: [7404256, 7469536)     wh1r: [7469536, 7600096)
//   Ph2 : [7600096, 10358176)
//   cd  : [6569368, 6731608)  keys: [6731608, 6772168)  sel: [6772168, 6774568)
//   mskg: [6774568, 6798568)  (u64[8*300*5]; inside dead w5r region)
// Peak = 16613376 floats = 66.5 MB.
// ---------------------------------------------------------------------------
extern "C" void kernel_launch(void* const* d_in, const int* in_sizes, int n_in,
                              void* d_out, int out_size, void* d_ws,
                              size_t ws_size, hipStream_t stream) {
  const float* images = (const float*)d_in[0];
  const float* w1 = (const float*)d_in[1];
  const float* b1 = (const float*)d_in[2];
  const float* w2 = (const float*)d_in[3];
  const float* b2 = (const float*)d_in[4];
  const float* w3 = (const float*)d_in[5];
  const float* b3 = (const float*)d_in[6];
  const float* w4 = (const float*)d_in[7];
  const float* b4 = (const float*)d_in[8];
  const float* w5 = (const float*)d_in[9];
  const float* b5 = (const float*)d_in[10];
  const float* wh1 = (const float*)d_in[11];
  const float* bh1 = (const float*)d_in[12];
  const float* wh2 = (const float*)d_in[13];
  const float* bh2 = (const float*)d_in[14];
  float* ws = (float*)d_ws;

  float* x1 = ws + 0;
  float* x2 = ws + 11075584;
  float* P3 = ws + 5537792;
  float* x3p = ws + 0;
  float* w4r = ws + 3200000;
  float* x4p = ws + 0;  // padded conv4 output, written after conv4 reads x3p
  float* f2 = ws + 4153344;
  float* x5 = ws + 5532384;
  float* f1 = ws + 6224608;
  float* cd = ws + 6569368;
  u64* keys = (u64*)(ws + 6731608);
  int* sel = (int*)(ws + 6772168);
  u64* mskg = (u64*)(ws + 6774568);
  float* P = ws + 11075584;
  float* w5r = ws + 6224608;
  float* wh2r = ws + 7404256;
  float* wh1r = ws + 7469536;
  float* Ph2 = ws + 7600096;

  // conv1: pair+z2 (1360 blocks: 4bp x 85x x 4g)
  k_conv1zp<<<1360, 256, 0, stream>>>(images, w1, b1, x1);
  // conv2: pair+z2 (704 blocks: 4bp x 22x x 8g)
  k_conv2zp<<<704, 256, 0, stream>>>(x1, w2, b2, x2);
  // conv3 pair+z2 (768) + w4 repack OCT=16 (160)
  k_conv3_repack<<<928, 256, 0, stream>>>(x2, w3, P3, w4, w4r);
  // fused conv3 reduce + bias + lrelu + zero-pad -> x3p (8*128*3024)
  k_reduce_pad3<<<12096, 256, 0, stream>>>(P3, b3, x3p);
  // conv4 z2 OCT=16 (768) + w5/wh2/wh1 repack (1024)
  k_conv4_repack<<<1792, 256, 0, stream>>>(x3p, w4r, P, w5, wh2, wh1, w5r, wh2r, wh1r);
  // fused conv4 reduce + bias + lrelu + zero-pad -> x4p (8*256*756)
  k_reduce_pad4<<<6048, 256, 0, stream>>>(P, b4, x4p);
  // conv5 z2 OCT=16 (1024) + head2 SPLIT=2 (720), both XCD-swizzled
  k_h2c5<<<1744, 256, 0, stream>>>(x4p, w5r, wh2r, P, Ph2);
  k_reduce_h2c5<<<2704 + 5388, 256, 0, stream>>>(P, Ph2, b5, bh2, x5, f2);
  // head1: split-K x16 -> 1920 blocks
  k_head1<<<dim3(1, 15, 128), 256, 0, stream>>>(x5, wh1r, P);
  reduce_bias<16, false><<<(344760 + 255) / 256, 256, 0, stream>>>(P, bh1, f1, 255, 169, 344760);

  decode_kernel<<<80, 256, 0, stream>>>(f1, f2, cd, keys);
  rank_select_kernel<<<dim3(40, 8), 256, 0, stream>>>(keys, sel);
  nms_mask_kernel<<<dim3(10, 8), 256, 0, stream>>>(cd, sel, mskg);
  nms_scan_kernel<<<8, 256, 0, stream>>>(cd, sel, mskg, (float*)d_out);
}